// Round 7
// baseline (239.505 us; speedup 1.0000x reference)
//
#include <hip/hip_runtime.h>
#include <hip/hip_bf16.h>
#include <math.h>

typedef __attribute__((ext_vector_type(4))) float f32x4;
typedef __attribute__((ext_vector_type(8))) short bf16x8;

#define N_ROWS 8192
#define D 256
#define MSHIFT 16.0f
#define NKB 8
#define KRANGE (N_ROWS / NKB)     // 1024
#define NSTEP (KRANGE / 32)       // 32

__device__ __forceinline__ unsigned short f2bf(float f) {
    unsigned int u = __float_as_uint(f);
    unsigned int r = u + 0x7FFFu + ((u >> 16) & 1u);
    return (unsigned short)(r >> 16);
}

__device__ __forceinline__ float breduce_sum256(float v, float* sb) {
#pragma unroll
    for (int off = 32; off; off >>= 1) v += __shfl_down(v, off);
    int wid = threadIdx.x >> 6;
    __syncthreads();
    if ((threadIdx.x & 63) == 0) sb[wid] = v;
    __syncthreads();
    return sb[0] + sb[1] + sb[2] + sb[3];
}

__device__ __forceinline__ void dma16(const void* g, void* l) {
    __builtin_amdgcn_global_load_lds(
        (const __attribute__((address_space(1))) unsigned int*)g,
        (__attribute__((address_space(3))) unsigned int*)l, 16, 0, 0);
}

__device__ __forceinline__ bf16x8 adj2bf(int4 a, int4 b) {
    bf16x8 r;
    r[0] = a.x ? (short)0x3F80 : (short)0;
    r[1] = a.y ? (short)0x3F80 : (short)0;
    r[2] = a.z ? (short)0x3F80 : (short)0;
    r[3] = a.w ? (short)0x3F80 : (short)0;
    r[4] = b.x ? (short)0x3F80 : (short)0;
    r[5] = b.y ? (short)0x3F80 : (short)0;
    r[6] = b.z ? (short)0x3F80 : (short)0;
    r[7] = b.w ? (short)0x3F80 : (short)0;
    return r;
}

// K2: M2[k][j] = sum_m W_gcn[k][m] * W_att[m+1][j]
__global__ void k_M2(const float* __restrict__ Wg, const float* __restrict__ Wa,
                     float* __restrict__ M2) {
    int k = blockIdx.x, t = threadIdx.x;
    float acc = 0.f;
#pragma unroll 8
    for (int m = 0; m < 255; ++m)
        acc += Wg[k * 255 + m] * Wa[(m + 1) * 256 + t];
    M2[k * 256 + t] = acc;
}

// K3: fused logmap0 + h-GEMV + attention-weight exp + direct GT write. 16 rows/block.
__global__ void k_h2(const float* __restrict__ x, const float* __restrict__ M2,
                     const float* __restrict__ aatt,
                     unsigned short* __restrict__ wbf, unsigned short* __restrict__ GT) {
    __shared__ float sb[4];
    __shared__ float Ls[16][256];
    int i0 = blockIdx.x * 16, t = threadIdx.x;
#pragma unroll
    for (int r = 0; r < 16; ++r) {
        float xv = x[(size_t)(i0 + r) * D + t];
        float yv = (t >= 1) ? xv : 0.f;
        float ss = breduce_sum256(yv * yv, sb);
        float ynorm = fmaxf(sqrtf(ss), 1e-15f);
        float x0 = x[(size_t)(i0 + r) * D];
        float th = fmaxf(x0, 1.f + 1e-7f);
        float al = acoshf(th);
        Ls[r][t] = (t >= 1) ? (al * yv / ynorm) : 0.f;
    }
    __syncthreads();
    float acc[16];
#pragma unroll
    for (int r = 0; r < 16; ++r) acc[r] = 0.f;
#pragma unroll 4
    for (int k = 0; k < 255; ++k) {
        float m2 = M2[k * 256 + t];
#pragma unroll
        for (int r = 0; r < 16; ++r) acc[r] += Ls[r][k + 1] * m2;
    }
    float a2 = aatt[256 + t];
    float wr[16];
#pragma unroll
    for (int r = 0; r < 16; ++r) {
        float s = breduce_sum256(acc[r] * a2, sb);
        wr[r] = expf(s - MSHIFT);
        if (t == r) wbf[i0 + r] = f2bf(wr[r]);
    }
    bf16x8 g0, g1;
#pragma unroll
    for (int r = 0; r < 8; ++r) {
        g0[r] = (short)f2bf(acc[r] * wr[r]);
        g1[r] = (short)f2bf(acc[r + 8] * wr[r + 8]);
    }
    *(bf16x8*)(GT + (size_t)t * N_ROWS + i0) = g0;
    *(bf16x8*)(GT + (size_t)t * N_ROWS + i0 + 8) = g1;
}

// K6: masked GEMM, adj read once in-loop. BM=64, BN=256, BK=32.
// XCD-PINNED split-K: kb = blockIdx&7 -> with round-robin block->XCD dispatch,
// every block on an XCD works the SAME GT k-slice (0.5 MB) => L2-resident,
// eliminating ~512 MB of L3-fabric re-reads. Correct under any mapping.
// Triple-buffered LDS DMA pipeline, one barrier/step, counted vmcnt(6).
__global__ void __launch_bounds__(256, 2)
k_attadj(const int* __restrict__ adj, const unsigned short* __restrict__ GT,
         const unsigned short* __restrict__ wbf, float* __restrict__ part,
         float* __restrict__ rspart) {
    __shared__ __align__(16) char bufA[3 * 8192];   // 3 x (64 rows x 32 ints)
    __shared__ __align__(16) char bufB[3 * 16384];  // 3 x (256 cols x 32 bf16)
    __shared__ __align__(16) char wlds[2048];       // KRANGE bf16 weights
    const int tid = threadIdx.x;
    const int kb = blockIdx.x & 7;          // XCD-pinned K-slice
    const int rb = blockIdx.x >> 3;         // 0..127
    const int i0 = rb * 64;
    const int kbeg = kb * KRANGE;
    const int w = tid >> 6, l = tid & 63;
    const int lr = l & 15, lq = l >> 4;

    // ---- DMA sources (pre-swizzled global addresses; LDS dests linear)
    const int a0 = w * 2, a1 = a0 + 1;
    const int ra0 = a0 * 8 + (l >> 3), ra1 = a1 * 8 + (l >> 3);
    const int pgA = (l & 7) ^ ((l >> 3) & 7);
    const int* srcA0 = adj + (size_t)(i0 + ra0) * N_ROWS + kbeg + pgA * 4;
    const int* srcA1 = adj + (size_t)(i0 + ra1) * N_ROWS + kbeg + pgA * 4;
    const int bswz = ((l >> 2) & 3) ^ ((l >> 4) & 3);
    const unsigned short* srcB0 = GT + (size_t)((w * 4 + 0) * 16 + (l >> 2)) * N_ROWS + kbeg + ((l & 3) ^ bswz) * 8;
    const unsigned short* srcB1 = GT + (size_t)((w * 4 + 1) * 16 + (l >> 2)) * N_ROWS + kbeg + ((l & 3) ^ bswz) * 8;
    const unsigned short* srcB2 = GT + (size_t)((w * 4 + 2) * 16 + (l >> 2)) * N_ROWS + kbeg + ((l & 3) ^ bswz) * 8;
    const unsigned short* srcB3 = GT + (size_t)((w * 4 + 3) * 16 + (l >> 2)) * N_ROWS + kbeg + ((l & 3) ^ bswz) * 8;

#define STAGE(t_, bi_) do {                                        \
        const int koff_ = (t_) * 32;                               \
        char* bA_ = bufA + (bi_) * 8192;                           \
        char* bB_ = bufB + (bi_) * 16384;                          \
        dma16(srcA0 + koff_, bA_ + a0 * 1024);                     \
        dma16(srcA1 + koff_, bA_ + a1 * 1024);                     \
        dma16(srcB0 + koff_, bB_ + (w * 4 + 0) * 1024);            \
        dma16(srcB1 + koff_, bB_ + (w * 4 + 1) * 1024);            \
        dma16(srcB2 + koff_, bB_ + (w * 4 + 2) * 1024);            \
        dma16(srcB3 + koff_, bB_ + (w * 4 + 3) * 1024);            \
    } while (0)

    f32x4 zero4 = {0.f, 0.f, 0.f, 0.f};
    f32x4 acc[4][4], acc_rs[4];
#pragma unroll
    for (int m = 0; m < 4; ++m) {
        acc_rs[m] = zero4;
#pragma unroll
        for (int n = 0; n < 4; ++n) acc[m][n] = zero4;
    }

    // prologue: weight tile first (oldest), then stage steps 0,1
    if (w < 2) dma16(wbf + kbeg + w * 512 + l * 8, wlds + w * 1024);
    STAGE(0, 0);
    STAGE(1, 1);

    // read-side swizzled offsets (lane-constant)
    const int gA0 = lr * 128 + (((2 * lq) ^ (lr & 7)) << 4);
    const int gA1 = lr * 128 + (((2 * lq + 1) ^ (lr & 7)) << 4);
    const int gB = lr * 64 + ((lq ^ (lr & 3) ^ ((lr >> 2) & 3)) << 4);

    int cb = 0;   // buffer index for step t
    for (int t = 0; t < NSTEP; ++t) {
        if (t == NSTEP - 1) asm volatile("s_waitcnt vmcnt(0)" ::: "memory");
        else                asm volatile("s_waitcnt vmcnt(6)" ::: "memory");
        __builtin_amdgcn_sched_barrier(0);
        __builtin_amdgcn_s_barrier();
        __builtin_amdgcn_sched_barrier(0);
        if (t + 2 < NSTEP) {
            int sb_ = (cb == 0) ? 2 : cb - 1;    // (t+2)%3
            STAGE(t + 2, sb_);
        }
        const char* bA = bufA + cb * 8192;
        const char* bB = bufB + cb * 16384;

        bf16x8 wf = {0, 0, 0, 0, 0, 0, 0, 0};
        if (lr == 0) wf = *(const bf16x8*)(wlds + t * 64 + lq * 16);

        bf16x8 af[4];
#pragma unroll
        for (int m = 0; m < 4; ++m) {
            int4 u = *(const int4*)(bA + m * 2048 + gA0);
            int4 v = *(const int4*)(bA + m * 2048 + gA1);
            af[m] = adj2bf(u, v);
        }
#pragma unroll
        for (int n = 0; n < 4; ++n) {
            bf16x8 bf = *(const bf16x8*)(bB + w * 4096 + n * 1024 + gB);
#pragma unroll
            for (int m = 0; m < 4; ++m)
                acc[m][n] = __builtin_amdgcn_mfma_f32_16x16x32_bf16(af[m], bf, acc[m][n], 0, 0, 0);
        }
#pragma unroll
        for (int m = 0; m < 4; ++m)
            acc_rs[m] = __builtin_amdgcn_mfma_f32_16x16x32_bf16(af[m], wf, acc_rs[m], 0, 0, 0);
        cb = (cb == 2) ? 0 : cb + 1;
    }
#undef STAGE

    // rowsum (col 0 of acc_rs; waves identical, wave 0 writes)
    if (w == 0 && lr == 0) {
#pragma unroll
        for (int m = 0; m < 4; ++m)
#pragma unroll
            for (int v = 0; v < 4; ++v)
                rspart[(size_t)kb * N_ROWS + i0 + m * 16 + lq * 4 + v] = acc_rs[m][v];
    }

    // C write (layout: col=lane&15, row=(lane>>4)*4+reg)
    float* pbase = part + (size_t)kb * N_ROWS * D;
#pragma unroll
    for (int m = 0; m < 4; ++m)
#pragma unroll
        for (int n = 0; n < 4; ++n) {
            int orow = i0 + m * 16 + lq * 4;
            int ocol = (w << 6) + (n << 4) + lr;
            float* op = pbase + (size_t)orow * D + ocol;
#pragma unroll
            for (int v = 0; v < 4; ++v) op[(size_t)v * D] = acc[m][n][v];
        }
}

// K7: split-K reduce + epilogue (divide, elu, proj, logmap0, sigmoid, expmap0)
__global__ void k_final3(const float* __restrict__ part, const float* __restrict__ rspart,
                         float* __restrict__ out) {
    __shared__ float sb[4];
    int row = blockIdx.x, t = threadIdx.x;
    float raw = 0.f, rs = 0.f;
#pragma unroll
    for (int kbi = 0; kbi < NKB; ++kbi) {
        raw += part[((size_t)kbi * N_ROWS + row) * D + t];
        rs += rspart[(size_t)kbi * N_ROWS + row];
    }
    float hp = raw / rs;
    float ey = 0.f;
    if (t >= 1) ey = (hp > 0.f) ? hp : expm1f(hp);
    float ss = breduce_sum256(ey * ey, sb);
    float x0 = sqrtf(1.f + ss);
    float th = fmaxf(x0, 1.f + 1e-7f);
    float al = acoshf(th);
    float yn = fmaxf(sqrtf(ss), 1e-15f);
    float u = (t >= 1) ? (al * ey / yn) : 0.f;
    float s = 1.f / (1.f + expf(-u));
    float s2 = (t >= 1) ? s * s : 0.f;
    float ssn = breduce_sum256(s2, sb);
    float xn = fmaxf(sqrtf(ssn), 1e-15f);
    float sh = sinhf(xn);
    float yf = (t >= 1) ? (sh * s / xn) : 0.f;
    float sy = breduce_sum256(yf * yf, sb);
    float res = (t == 0) ? sqrtf(1.f + sy) : yf;
    out[(size_t)row * D + t] = res;
}

extern "C" void kernel_launch(void* const* d_in, const int* in_sizes, int n_in,
                              void* d_out, int out_size, void* d_ws, size_t ws_size,
                              hipStream_t stream) {
    const float* x    = (const float*)d_in[0];
    const int*   adj  = (const int*)d_in[1];
    const float* Wg   = (const float*)d_in[3];
    const float* Wa   = (const float*)d_in[4];
    const float* aatt = (const float*)d_in[5];
    float* out = (float*)d_out;

    char* wsb = (char*)d_ws;
    float*          M2     = (float*)(wsb);                      // 256 KB
    unsigned short* GT     = (unsigned short*)(wsb + 0x0040000); // 4 MB
    unsigned short* wbf    = (unsigned short*)(wsb + 0x0440000); // 16 KB
    float*          rspart = (float*)(wsb + 0x0448000);          // 256 KB
    float*          part   = (float*)(wsb + 0x04C0000);          // 64 MB

    k_M2<<<255, 256, 0, stream>>>(Wg, Wa, M2);
    k_h2<<<N_ROWS / 16, 256, 0, stream>>>(x, M2, aatt, wbf, GT);
    k_attadj<<<128 * NKB, 256, 0, stream>>>(adj, GT, wbf, part, rspart);
    k_final3<<<N_ROWS, 256, 0, stream>>>(part, rspart, out);
}

// Round 8
// 184.862 us; speedup vs baseline: 1.2956x; 1.2956x over previous
//
#include <hip/hip_runtime.h>
#include <hip/hip_bf16.h>
#include <math.h>

typedef __attribute__((ext_vector_type(4))) float f32x4;
typedef __attribute__((ext_vector_type(8))) short bf16x8;

#define N_ROWS 8192
#define D 256
#define MSHIFT 16.0f
#define NKB 4
#define KRANGE (N_ROWS / NKB)     // 2048
#define NSTEP (KRANGE / 64)       // 32

__device__ __forceinline__ unsigned short f2bf(float f) {
    unsigned int u = __float_as_uint(f);
    unsigned int r = u + 0x7FFFu + ((u >> 16) & 1u);
    return (unsigned short)(r >> 16);
}
__device__ __forceinline__ float bf2f(unsigned short h) {
    return __uint_as_float(((unsigned int)h) << 16);
}

__device__ __forceinline__ float breduce_sum256(float v, float* sb) {
#pragma unroll
    for (int off = 32; off; off >>= 1) v += __shfl_down(v, off);
    int wid = threadIdx.x >> 6;
    __syncthreads();
    if ((threadIdx.x & 63) == 0) sb[wid] = v;
    __syncthreads();
    return sb[0] + sb[1] + sb[2] + sb[3];
}

__device__ __forceinline__ void dma16(const void* g, void* l) {
    __builtin_amdgcn_global_load_lds(
        (const __attribute__((address_space(1))) unsigned int*)g,
        (__attribute__((address_space(3))) unsigned int*)l, 16, 0, 0);
}

__device__ __forceinline__ bf16x8 adj2bf(int4 a, int4 b) {
    bf16x8 r;
    r[0] = a.x ? (short)0x3F80 : (short)0;
    r[1] = a.y ? (short)0x3F80 : (short)0;
    r[2] = a.z ? (short)0x3F80 : (short)0;
    r[3] = a.w ? (short)0x3F80 : (short)0;
    r[4] = b.x ? (short)0x3F80 : (short)0;
    r[5] = b.y ? (short)0x3F80 : (short)0;
    r[6] = b.z ? (short)0x3F80 : (short)0;
    r[7] = b.w ? (short)0x3F80 : (short)0;
    return r;
}

// K1: M2 row k (f32) -> M2T hi/lo bf16 split [j][k]; v[k] = sum_j M2[k][j]*a2[j]
__global__ void k_M2v(const float* __restrict__ Wg, const float* __restrict__ Wa,
                      const float* __restrict__ aatt,
                      unsigned short* __restrict__ M2Thi, unsigned short* __restrict__ M2Tlo,
                      float* __restrict__ v) {
    __shared__ float sb[4];
    int k = blockIdx.x, t = threadIdx.x;
    float acc = 0.f;
#pragma unroll 8
    for (int m = 0; m < 255; ++m)
        acc += Wg[k * 255 + m] * Wa[(m + 1) * 256 + t];
    unsigned short hi = f2bf(acc);
    unsigned short lo = f2bf(acc - bf2f(hi));
    M2Thi[t * 256 + k] = hi;
    M2Tlo[t * 256 + k] = lo;
    if (k == 0) { M2Thi[t * 256 + 255] = 0; M2Tlo[t * 256 + 255] = 0; }
    float s = breduce_sum256(acc * aatt[256 + t], sb);
    if (t == 0) v[k] = s;
}

// K2: per-row logmap0 + c = logx.v + wexp; write wbf and w-scaled logx hi/lo bf16 (k-shifted)
__global__ void k_logw(const float* __restrict__ x, const float* __restrict__ v,
                       unsigned short* __restrict__ wbf,
                       unsigned short* __restrict__ Awhi, unsigned short* __restrict__ Awlo) {
    __shared__ float sb[4];
    int i0 = blockIdx.x * 8, t = threadIdx.x;
    float vv = (t >= 1) ? v[t - 1] : 0.f;
#pragma unroll
    for (int r = 0; r < 8; ++r) {
        float xv = x[(size_t)(i0 + r) * D + t];
        float yv = (t >= 1) ? xv : 0.f;
        float ss = breduce_sum256(yv * yv, sb);
        float x0 = x[(size_t)(i0 + r) * D];
        float coef = acoshf(fmaxf(x0, 1.f + 1e-7f)) / fmaxf(sqrtf(ss), 1e-15f);
        float lg = coef * yv;                 // logx[i][t]
        float c = breduce_sum256(lg * vv, sb);
        float w = expf(c - MSHIFT);
        if (t == r) wbf[i0 + r] = f2bf(w);
        float aw = w * lg;
        unsigned short hi = f2bf(aw);
        unsigned short lo = f2bf(aw - bf2f(hi));
        int kd = (t == 0) ? 255 : (t - 1);    // Aw[i][k] = w*logx[i][k+1], pad k=255 -> 0
        Awhi[(size_t)(i0 + r) * 256 + kd] = hi;
        Awlo[(size_t)(i0 + r) * 256 + kd] = lo;
    }
}

// K3: GT[c][i] = sum_k M2T[c][k] * Aw[i][k]  (3-term hi/lo MFMA). 512 thr, 64 i-cols/block.
__global__ void __launch_bounds__(512)
k_hGT(const unsigned short* __restrict__ M2Thi, const unsigned short* __restrict__ M2Tlo,
      const unsigned short* __restrict__ Awhi, const unsigned short* __restrict__ Awlo,
      unsigned short* __restrict__ GT) {
    __shared__ __align__(16) char ahi[32768], alo[32768], bhi[8192], blo[8192];
    const int tid = threadIdx.x;
    const int w = tid >> 6, l = tid & 63;
    const int lr = l & 15, lq = l >> 4;
    const int i0 = blockIdx.x * 64;
    const int gs = (l & 7) ^ (l >> 3);

    // DMA sources (pre-swizzled granule; linear LDS dest)
    const unsigned short* srcAhi[4];
    const unsigned short* srcAlo[4];
#pragma unroll
    for (int i = 0; i < 4; ++i) {
        int rowA = (w * 4 + i) * 8 + (l >> 3);
        srcAhi[i] = M2Thi + rowA * 256 + gs * 8;
        srcAlo[i] = M2Tlo + rowA * 256 + gs * 8;
    }
    int rowB = w * 8 + (l >> 3);
    const unsigned short* srcBhi = Awhi + (size_t)(i0 + rowB) * 256 + gs * 8;
    const unsigned short* srcBlo = Awlo + (size_t)(i0 + rowB) * 256 + gs * 8;

    f32x4 zero4 = {0.f, 0.f, 0.f, 0.f};
    f32x4 acc[2][4];
#pragma unroll
    for (int m = 0; m < 2; ++m)
#pragma unroll
        for (int n = 0; n < 4; ++n) acc[m][n] = zero4;

    for (int t = 0; t < 4; ++t) {
        if (t) __syncthreads();
#pragma unroll
        for (int i = 0; i < 4; ++i) {
            dma16(srcAhi[i] + t * 64, ahi + (w * 4 + i) * 1024);
            dma16(srcAlo[i] + t * 64, alo + (w * 4 + i) * 1024);
        }
        dma16(srcBhi + t * 64, bhi + w * 1024);
        dma16(srcBlo + t * 64, blo + w * 1024);
        asm volatile("s_waitcnt vmcnt(0)" ::: "memory");
        __syncthreads();
#pragma unroll
        for (int ks = 0; ks < 2; ++ks) {
            const int g = ((ks * 4 + lq) ^ (lr & 7)) * 16;
            bf16x8 afh[2], afl[2];
#pragma unroll
            for (int m = 0; m < 2; ++m) {
                int row = w * 32 + m * 16 + lr;
                afh[m] = *(const bf16x8*)(ahi + row * 128 + g);
                afl[m] = *(const bf16x8*)(alo + row * 128 + g);
            }
#pragma unroll
            for (int n = 0; n < 4; ++n) {
                int rb = n * 16 + lr;
                bf16x8 bfh = *(const bf16x8*)(bhi + rb * 128 + g);
                bf16x8 bfl = *(const bf16x8*)(blo + rb * 128 + g);
#pragma unroll
                for (int m = 0; m < 2; ++m) {
                    acc[m][n] = __builtin_amdgcn_mfma_f32_16x16x32_bf16(afh[m], bfh, acc[m][n], 0, 0, 0);
                    acc[m][n] = __builtin_amdgcn_mfma_f32_16x16x32_bf16(afh[m], bfl, acc[m][n], 0, 0, 0);
                    acc[m][n] = __builtin_amdgcn_mfma_f32_16x16x32_bf16(afl[m], bfh, acc[m][n], 0, 0, 0);
                }
            }
        }
    }
    // store GT[c][i], c = w*32+m*16+lq*4+vv, i = i0+n*16+lr  (16-lane 32B segments)
#pragma unroll
    for (int m = 0; m < 2; ++m)
#pragma unroll
        for (int n = 0; n < 4; ++n)
#pragma unroll
            for (int vv = 0; vv < 4; ++vv) {
                int c = w * 32 + m * 16 + lq * 4 + vv;
                GT[(size_t)c * N_ROWS + i0 + n * 16 + lr] = f2bf(acc[m][n][vv]);
            }
}

// K4: masked GEMM, adj read once in-loop. BM=128, BN=256, BK=64, 2x2 wave split.
// Depth-2 LDS DMA pipeline, ONE barrier/step, counted vmcnt(16). All segments 128B.
__global__ void __launch_bounds__(256)
k_attadj(const int* __restrict__ adj, const unsigned short* __restrict__ GT,
         const unsigned short* __restrict__ wbf, float* __restrict__ part,
         float* __restrict__ rspart) {
    __shared__ __align__(16) char bufA[2][32768];  // 128 rows x 64 ints (256 B rows)
    __shared__ __align__(16) char bufB[2][32768];  // 256 cols x 64 bf16 (128 B rows)
    __shared__ __align__(16) char wlds[4096];      // KRANGE bf16 weights
    const int tid = threadIdx.x;
    const int kb = blockIdx.x & 3;          // low bits: all blocks on an XCD share a GT slice
    const int rb = blockIdx.x >> 2;         // 0..63
    const int i0 = rb * 128;
    const int kbeg = kb * KRANGE;
    const int w = tid >> 6, l = tid & 63;
    const int lr = l & 15, lq = l >> 4;
    const int wm = w >> 1, wn = w & 1;

    // A sources: inst a = w*8+i covers rows a*4..a*4+3; 16B granule (l&15)^(row&15)
    const int* srcA[8];
#pragma unroll
    for (int i = 0; i < 8; ++i) {
        int a = w * 8 + i;
        int row = a * 4 + (l >> 4);
        int gsrc = (l & 15) ^ (row & 15);
        srcA[i] = adj + (size_t)(i0 + row) * N_ROWS + kbeg + gsrc * 4;
    }
    // B sources: inst b = w*8+i covers cols b*8..b*8+7; 16B granule (l&7)^(l>>3)
    const unsigned short* srcB[8];
    const int gsB = (l & 7) ^ (l >> 3);
#pragma unroll
    for (int i = 0; i < 8; ++i) {
        int b = w * 8 + i;
        int col = b * 8 + (l >> 3);
        srcB[i] = GT + (size_t)col * N_ROWS + kbeg + gsB * 8;
    }

#define STAGE(t_, bi_) do {                                         \
        char* bA_ = bufA[bi_]; char* bB_ = bufB[bi_];               \
        _Pragma("unroll")                                           \
        for (int i_ = 0; i_ < 8; ++i_) {                            \
            dma16(srcA[i_] + (t_) * 64, bA_ + (w * 8 + i_) * 1024); \
            dma16(srcB[i_] + (t_) * 64, bB_ + (w * 8 + i_) * 1024); \
        }                                                           \
    } while (0)

    f32x4 zero4 = {0.f, 0.f, 0.f, 0.f};
    f32x4 acc[4][8], acc_rs[4];
#pragma unroll
    for (int m = 0; m < 4; ++m) {
        acc_rs[m] = zero4;
#pragma unroll
        for (int n = 0; n < 8; ++n) acc[m][n] = zero4;
    }

    // prologue: weight slice + step 0
    dma16(wbf + kbeg + (w * 64 + l) * 8, wlds + w * 1024);
    STAGE(0, 0);

    for (int t = 0; t < NSTEP; ++t) {
        __builtin_amdgcn_s_barrier();       // prev compute done -> buf[(t+1)&1] free
        if (t + 1 < NSTEP) {
            STAGE(t + 1, (t + 1) & 1);
            asm volatile("s_waitcnt vmcnt(16)" ::: "memory");  // STAGE(t) landed
        } else {
            asm volatile("s_waitcnt vmcnt(0)" ::: "memory");
        }
        __builtin_amdgcn_sched_barrier(0);
        const char* bA = bufA[t & 1];
        const char* bB = bufB[t & 1];
#pragma unroll
        for (int ks = 0; ks < 2; ++ks) {
            bf16x8 af[4];
#pragma unroll
            for (int m = 0; m < 4; ++m) {
                int row = wm * 64 + m * 16 + lr;
                int4 u = *(const int4*)(bA + row * 256 + (((ks * 8 + lq * 2) ^ lr)) * 16);
                int4 q = *(const int4*)(bA + row * 256 + (((ks * 8 + lq * 2 + 1) ^ lr)) * 16);
                af[m] = adj2bf(u, q);
            }
            bf16x8 wf = {0, 0, 0, 0, 0, 0, 0, 0};
            if (lr == 0) wf = *(const bf16x8*)(wlds + t * 128 + ks * 64 + lq * 16);
#pragma unroll
            for (int n = 0; n < 8; ++n) {
                int col = wn * 128 + n * 16 + lr;
                bf16x8 bf = *(const bf16x8*)(bB + col * 128 + (((ks * 4 + lq) ^ (lr & 7))) * 16);
#pragma unroll
                for (int m = 0; m < 4; ++m)
                    acc[m][n] = __builtin_amdgcn_mfma_f32_16x16x32_bf16(af[m], bf, acc[m][n], 0, 0, 0);
            }
#pragma unroll
            for (int m = 0; m < 4; ++m)
                acc_rs[m] = __builtin_amdgcn_mfma_f32_16x16x32_bf16(af[m], wf, acc_rs[m], 0, 0, 0);
        }
    }
#undef STAGE

    // rowsum (col 0 of acc_rs; wn duplicates -> wn==0 writes)
    if (wn == 0 && lr == 0) {
#pragma unroll
        for (int m = 0; m < 4; ++m)
#pragma unroll
            for (int vv = 0; vv < 4; ++vv)
                rspart[(size_t)kb * N_ROWS + i0 + wm * 64 + m * 16 + lq * 4 + vv] = acc_rs[m][vv];
    }

    // C write (layout: col=lane&15, row=(lane>>4)*4+reg)
    float* pbase = part + (size_t)kb * N_ROWS * D;
#pragma unroll
    for (int m = 0; m < 4; ++m)
#pragma unroll
        for (int n = 0; n < 8; ++n) {
            int orow = i0 + wm * 64 + m * 16 + lq * 4;
            int ocol = wn * 128 + n * 16 + lr;
            float* op = pbase + (size_t)orow * D + ocol;
#pragma unroll
            for (int vv = 0; vv < 4; ++vv) op[(size_t)vv * D] = acc[m][n][vv];
        }
}

// K5: split-K reduce + epilogue (divide, elu, proj, logmap0, sigmoid, expmap0)
__global__ void k_final3(const float* __restrict__ part, const float* __restrict__ rspart,
                         float* __restrict__ out) {
    __shared__ float sb[4];
    int row = blockIdx.x, t = threadIdx.x;
    float raw = 0.f, rs = 0.f;
#pragma unroll
    for (int kbi = 0; kbi < NKB; ++kbi) {
        raw += part[((size_t)kbi * N_ROWS + row) * D + t];
        rs += rspart[(size_t)kbi * N_ROWS + row];
    }
    float hp = raw / rs;
    float ey = 0.f;
    if (t >= 1) ey = (hp > 0.f) ? hp : expm1f(hp);
    float ss = breduce_sum256(ey * ey, sb);
    float x0 = sqrtf(1.f + ss);
    float th = fmaxf(x0, 1.f + 1e-7f);
    float al = acoshf(th);
    float yn = fmaxf(sqrtf(ss), 1e-15f);
    float u = (t >= 1) ? (al * ey / yn) : 0.f;
    float s = 1.f / (1.f + expf(-u));
    float s2 = (t >= 1) ? s * s : 0.f;
    float ssn = breduce_sum256(s2, sb);
    float xn = fmaxf(sqrtf(ssn), 1e-15f);
    float sh = sinhf(xn);
    float yf = (t >= 1) ? (sh * s / xn) : 0.f;
    float sy = breduce_sum256(yf * yf, sb);
    float res = (t == 0) ? sqrtf(1.f + sy) : yf;
    out[(size_t)row * D + t] = res;
}

extern "C" void kernel_launch(void* const* d_in, const int* in_sizes, int n_in,
                              void* d_out, int out_size, void* d_ws, size_t ws_size,
                              hipStream_t stream) {
    const float* x    = (const float*)d_in[0];
    const int*   adj  = (const int*)d_in[1];
    const float* Wg   = (const float*)d_in[3];
    const float* Wa   = (const float*)d_in[4];
    const float* aatt = (const float*)d_in[5];
    float* out = (float*)d_out;

    char* wsb = (char*)d_ws;
    unsigned short* M2Thi  = (unsigned short*)(wsb);              // 128 KB
    unsigned short* M2Tlo  = (unsigned short*)(wsb + 0x0020000);  // 128 KB
    float*          v      = (float*)(wsb + 0x0040000);           // 1 KB
    unsigned short* wbf    = (unsigned short*)(wsb + 0x0048000);  // 16 KB
    unsigned short* Awhi   = (unsigned short*)(wsb + 0x0100000);  // 4 MB
    unsigned short* Awlo   = (unsigned short*)(wsb + 0x0500000);  // 4 MB
    unsigned short* GT     = (unsigned short*)(wsb + 0x0900000);  // 4 MB
    float*          rspart = (float*)(wsb + 0x0D00000);           // 128 KB
    float*          part   = (float*)(wsb + 0x1000000);           // 32 MB

    k_M2v<<<255, 256, 0, stream>>>(Wg, Wa, aatt, M2Thi, M2Tlo, v);
    k_logw<<<N_ROWS / 8, 256, 0, stream>>>(x, v, wbf, Awhi, Awlo);
    k_hGT<<<N_ROWS / 64, 512, 0, stream>>>(M2Thi, M2Tlo, Awhi, Awlo, GT);
    k_attadj<<<64 * NKB, 256, 0, stream>>>(adj, GT, wbf, part, rspart);
    k_final3<<<N_ROWS, 256, 0, stream>>>(part, rspart, out);
}

// Round 9
// 182.027 us; speedup vs baseline: 1.3158x; 1.0156x over previous
//
#include <hip/hip_runtime.h>
#include <hip/hip_bf16.h>
#include <math.h>

typedef __attribute__((ext_vector_type(4))) float f32x4;
typedef __attribute__((ext_vector_type(8))) short bf16x8;

#define N_ROWS 8192
#define D 256
#define MSHIFT 16.0f
#define NKB 4
#define KRANGE (N_ROWS / NKB)     // 2048
#define NSTEP (KRANGE / 64)       // 32

__device__ __forceinline__ unsigned short f2bf(float f) {
    unsigned int u = __float_as_uint(f);
    unsigned int r = u + 0x7FFFu + ((u >> 16) & 1u);
    return (unsigned short)(r >> 16);
}
__device__ __forceinline__ float bf2f(unsigned short h) {
    return __uint_as_float(((unsigned int)h) << 16);
}

__device__ __forceinline__ float breduce_sum256(float v, float* sb) {
#pragma unroll
    for (int off = 32; off; off >>= 1) v += __shfl_down(v, off);
    int wid = threadIdx.x >> 6;
    __syncthreads();
    if ((threadIdx.x & 63) == 0) sb[wid] = v;
    __syncthreads();
    return sb[0] + sb[1] + sb[2] + sb[3];
}

__device__ __forceinline__ void dma16(const void* g, void* l) {
    __builtin_amdgcn_global_load_lds(
        (const __attribute__((address_space(1))) unsigned int*)g,
        (__attribute__((address_space(3))) unsigned int*)l, 16, 0, 0);
}

__device__ __forceinline__ bf16x8 adj2bf(int4 a, int4 b) {
    bf16x8 r;
    r[0] = a.x ? (short)0x3F80 : (short)0;
    r[1] = a.y ? (short)0x3F80 : (short)0;
    r[2] = a.z ? (short)0x3F80 : (short)0;
    r[3] = a.w ? (short)0x3F80 : (short)0;
    r[4] = b.x ? (short)0x3F80 : (short)0;
    r[5] = b.y ? (short)0x3F80 : (short)0;
    r[6] = b.z ? (short)0x3F80 : (short)0;
    r[7] = b.w ? (short)0x3F80 : (short)0;
    return r;
}

// K1: M2 row k (f32) -> M2T hi/lo bf16 split [j][k]; v[k] = sum_j M2[k][j]*a2[j]
__global__ void k_M2v(const float* __restrict__ Wg, const float* __restrict__ Wa,
                      const float* __restrict__ aatt,
                      unsigned short* __restrict__ M2Thi, unsigned short* __restrict__ M2Tlo,
                      float* __restrict__ v) {
    __shared__ float sb[4];
    int k = blockIdx.x, t = threadIdx.x;
    float acc = 0.f;
#pragma unroll 8
    for (int m = 0; m < 255; ++m)
        acc += Wg[k * 255 + m] * Wa[(m + 1) * 256 + t];
    unsigned short hi = f2bf(acc);
    unsigned short lo = f2bf(acc - bf2f(hi));
    M2Thi[t * 256 + k] = hi;
    M2Tlo[t * 256 + k] = lo;
    if (k == 0) { M2Thi[t * 256 + 255] = 0; M2Tlo[t * 256 + 255] = 0; }
    float s = breduce_sum256(acc * aatt[256 + t], sb);
    if (t == 0) v[k] = s;
}

// K2: per-row logmap0 + c = logx.v + wexp; write wbf and w-scaled logx hi/lo bf16 (k-shifted)
__global__ void k_logw(const float* __restrict__ x, const float* __restrict__ v,
                       unsigned short* __restrict__ wbf,
                       unsigned short* __restrict__ Awhi, unsigned short* __restrict__ Awlo) {
    __shared__ float sb[4];
    int i0 = blockIdx.x * 8, t = threadIdx.x;
    float vv = (t >= 1) ? v[t - 1] : 0.f;
#pragma unroll
    for (int r = 0; r < 8; ++r) {
        float xv = x[(size_t)(i0 + r) * D + t];
        float yv = (t >= 1) ? xv : 0.f;
        float ss = breduce_sum256(yv * yv, sb);
        float x0 = x[(size_t)(i0 + r) * D];
        float coef = acoshf(fmaxf(x0, 1.f + 1e-7f)) / fmaxf(sqrtf(ss), 1e-15f);
        float lg = coef * yv;                 // logx[i][t]
        float c = breduce_sum256(lg * vv, sb);
        float w = expf(c - MSHIFT);
        if (t == r) wbf[i0 + r] = f2bf(w);
        float aw = w * lg;
        unsigned short hi = f2bf(aw);
        unsigned short lo = f2bf(aw - bf2f(hi));
        int kd = (t == 0) ? 255 : (t - 1);    // Aw[i][k] = w*logx[i][k+1], pad k=255 -> 0
        Awhi[(size_t)(i0 + r) * 256 + kd] = hi;
        Awlo[(size_t)(i0 + r) * 256 + kd] = lo;
    }
}

// K3: GT[c][i] = sum_k M2T[c][k] * Aw[i][k]  (3-term hi/lo MFMA). 512 thr, 64 i-cols/block.
__global__ void __launch_bounds__(512)
k_hGT(const unsigned short* __restrict__ M2Thi, const unsigned short* __restrict__ M2Tlo,
      const unsigned short* __restrict__ Awhi, const unsigned short* __restrict__ Awlo,
      unsigned short* __restrict__ GT) {
    __shared__ __align__(16) char ahi[32768], alo[32768], bhi[8192], blo[8192];
    const int tid = threadIdx.x;
    const int w = tid >> 6, l = tid & 63;
    const int lr = l & 15, lq = l >> 4;
    const int i0 = blockIdx.x * 64;
    const int gs = (l & 7) ^ (l >> 3);

    const unsigned short* srcAhi[4];
    const unsigned short* srcAlo[4];
#pragma unroll
    for (int i = 0; i < 4; ++i) {
        int rowA = (w * 4 + i) * 8 + (l >> 3);
        srcAhi[i] = M2Thi + rowA * 256 + gs * 8;
        srcAlo[i] = M2Tlo + rowA * 256 + gs * 8;
    }
    int rowB = w * 8 + (l >> 3);
    const unsigned short* srcBhi = Awhi + (size_t)(i0 + rowB) * 256 + gs * 8;
    const unsigned short* srcBlo = Awlo + (size_t)(i0 + rowB) * 256 + gs * 8;

    f32x4 zero4 = {0.f, 0.f, 0.f, 0.f};
    f32x4 acc[2][4];
#pragma unroll
    for (int m = 0; m < 2; ++m)
#pragma unroll
        for (int n = 0; n < 4; ++n) acc[m][n] = zero4;

    for (int t = 0; t < 4; ++t) {
        if (t) __syncthreads();
#pragma unroll
        for (int i = 0; i < 4; ++i) {
            dma16(srcAhi[i] + t * 64, ahi + (w * 4 + i) * 1024);
            dma16(srcAlo[i] + t * 64, alo + (w * 4 + i) * 1024);
        }
        dma16(srcBhi + t * 64, bhi + w * 1024);
        dma16(srcBlo + t * 64, blo + w * 1024);
        asm volatile("s_waitcnt vmcnt(0)" ::: "memory");
        __syncthreads();
#pragma unroll
        for (int ks = 0; ks < 2; ++ks) {
            const int g = ((ks * 4 + lq) ^ (lr & 7)) * 16;
            bf16x8 afh[2], afl[2];
#pragma unroll
            for (int m = 0; m < 2; ++m) {
                int row = w * 32 + m * 16 + lr;
                afh[m] = *(const bf16x8*)(ahi + row * 128 + g);
                afl[m] = *(const bf16x8*)(alo + row * 128 + g);
            }
#pragma unroll
            for (int n = 0; n < 4; ++n) {
                int rb = n * 16 + lr;
                bf16x8 bfh = *(const bf16x8*)(bhi + rb * 128 + g);
                bf16x8 bfl = *(const bf16x8*)(blo + rb * 128 + g);
#pragma unroll
                for (int m = 0; m < 2; ++m) {
                    acc[m][n] = __builtin_amdgcn_mfma_f32_16x16x32_bf16(afh[m], bfh, acc[m][n], 0, 0, 0);
                    acc[m][n] = __builtin_amdgcn_mfma_f32_16x16x32_bf16(afh[m], bfl, acc[m][n], 0, 0, 0);
                    acc[m][n] = __builtin_amdgcn_mfma_f32_16x16x32_bf16(afl[m], bfh, acc[m][n], 0, 0, 0);
                }
            }
        }
    }
#pragma unroll
    for (int m = 0; m < 2; ++m)
#pragma unroll
        for (int n = 0; n < 4; ++n)
#pragma unroll
            for (int vv = 0; vv < 4; ++vv) {
                int c = w * 32 + m * 16 + lq * 4 + vv;
                GT[(size_t)c * N_ROWS + i0 + n * 16 + lr] = f2bf(acc[m][n][vv]);
            }
}

// K4: masked GEMM. BM=64, BN=256, BK=64. 512 thr (8 waves, 4x2 split), 2 blocks/CU.
// A: global->VGPR direct (distance-1 prefetch, natural fragment coalescing).
// B: dma16 double-buffer, ONE barrier/step, wait-BEFORE-barrier (race-free), vmcnt(4).
// kb in low 2 bits -> XCD-pinned GT slice (intra-step L2 reuse by 64 blocks/XCD).
__global__ void __launch_bounds__(512, 4)
k_attadj(const int* __restrict__ adj, const unsigned short* __restrict__ GT,
         const unsigned short* __restrict__ wbf, float* __restrict__ part,
         float* __restrict__ rspart) {
    __shared__ __align__(16) char bufB[2][32768];  // 256 cols x 64 bf16 (128 B rows)
    __shared__ __align__(16) char wlds[4096];      // KRANGE bf16 weights
    const int tid = threadIdx.x;
    const int kb = blockIdx.x & 3;
    const int rb = blockIdx.x >> 2;        // 0..127
    const int i0 = rb * 64;
    const int kbeg = kb * KRANGE;
    const int w = tid >> 6, l = tid & 63;
    const int lr = l & 15, lq = l >> 4;
    const int wm = w >> 1, wn = w & 1;     // 4 row-groups x 2 col-groups

    // A: lane (lr,lq) covers row i0+wm*16+lr, k-chunk lq*8 within each 64-int step
    const int* aRow = adj + (size_t)(i0 + wm * 16 + lr) * N_ROWS + kbeg + lq * 8;

    // B dma sources: inst b=w*4+i, col=b*8+(l>>3), 16B granule (l&7)^(l>>3)
    const unsigned short* srcB[4];
#pragma unroll
    for (int i = 0; i < 4; ++i) {
        int b = w * 4 + i;
        srcB[i] = GT + (size_t)(b * 8 + (l >> 3)) * N_ROWS + kbeg + ((l & 7) ^ (l >> 3)) * 8;
    }

#define STAGEB(T_, BI_) do {                                          \
        _Pragma("unroll")                                             \
        for (int i_ = 0; i_ < 4; ++i_)                                \
            dma16(srcB[i_] + (T_) * 64, bufB[BI_] + (w * 4 + i_) * 1024); \
    } while (0)

#define LOADA(DST_, T_) do {                                          \
        _Pragma("unroll")                                             \
        for (int ks_ = 0; ks_ < 2; ++ks_) {                           \
            DST_[ks_ * 2 + 0] = *(const int4*)(aRow + (T_) * 64 + ks_ * 32);     \
            DST_[ks_ * 2 + 1] = *(const int4*)(aRow + (T_) * 64 + ks_ * 32 + 4); \
        }                                                             \
    } while (0)

    f32x4 zero4 = {0.f, 0.f, 0.f, 0.f};
    f32x4 acc[8], acc_rs = zero4;
#pragma unroll
    for (int n = 0; n < 8; ++n) acc[n] = zero4;

#define COMPUTE(T_, ACUR_) do {                                       \
        const char* bB_ = bufB[(T_) & 1];                             \
        _Pragma("unroll")                                             \
        for (int ks_ = 0; ks_ < 2; ++ks_) {                           \
            bf16x8 af_ = adj2bf(ACUR_[ks_ * 2], ACUR_[ks_ * 2 + 1]);  \
            bf16x8 wf_ = {0, 0, 0, 0, 0, 0, 0, 0};                    \
            if (lr == 0) wf_ = *(const bf16x8*)(wlds + (T_) * 128 + ks_ * 64 + lq * 16); \
            acc_rs = __builtin_amdgcn_mfma_f32_16x16x32_bf16(af_, wf_, acc_rs, 0, 0, 0); \
            _Pragma("unroll")                                         \
            for (int n_ = 0; n_ < 8; ++n_) {                          \
                bf16x8 bf_ = *(const bf16x8*)(bB_ + (wn * 128 + n_ * 16 + lr) * 128 + (((ks_ * 4 + lq) ^ (lr & 7))) * 16); \
                acc[n_] = __builtin_amdgcn_mfma_f32_16x16x32_bf16(af_, bf_, acc[n_], 0, 0, 0); \
            }                                                         \
        }                                                             \
    } while (0)

    int4 aA[4], aB_[4];
    // prologue: B(0)+wlds (older), then A(0) (newer) -> wait vmcnt(4) drains B0+wlds
    STAGEB(0, 0);
    if (w < 4) dma16(wbf + kbeg + w * 512 + l * 8, wlds + w * 1024);
    __builtin_amdgcn_sched_barrier(0);
    LOADA(aA, 0);
    __builtin_amdgcn_sched_barrier(0);

    for (int t = 0; t < NSTEP; t += 2) {
        // ---- step t (uses aA / bufB[t&1]; prefetches t+1)
        asm volatile("s_waitcnt vmcnt(4)" ::: "memory");   // drains B(t); leaves A(t)
        __builtin_amdgcn_sched_barrier(0);
        __builtin_amdgcn_s_barrier();                       // all waves' B(t) visible
        __builtin_amdgcn_sched_barrier(0);
        if (t + 1 < NSTEP) STAGEB(t + 1, (t + 1) & 1);
        __builtin_amdgcn_sched_barrier(0);
        if (t + 1 < NSTEP) LOADA(aB_, t + 1);
        __builtin_amdgcn_sched_barrier(0);
        COMPUTE(t, aA);
        // ---- step t+1 (uses aB_ / bufB[(t+1)&1]; prefetches t+2)
        asm volatile("s_waitcnt vmcnt(4)" ::: "memory");
        __builtin_amdgcn_sched_barrier(0);
        __builtin_amdgcn_s_barrier();
        __builtin_amdgcn_sched_barrier(0);
        if (t + 2 < NSTEP) STAGEB(t + 2, (t + 2) & 1);
        __builtin_amdgcn_sched_barrier(0);
        if (t + 2 < NSTEP) LOADA(aA, t + 2);
        __builtin_amdgcn_sched_barrier(0);
        COMPUTE(t + 1, aB_);
    }
#undef STAGEB
#undef LOADA
#undef COMPUTE

    // rowsum (col 0 of acc_rs; wn duplicates -> wn==0 writes)
    if (wn == 0 && lr == 0) {
#pragma unroll
        for (int vv = 0; vv < 4; ++vv)
            rspart[(size_t)kb * N_ROWS + i0 + wm * 16 + lq * 4 + vv] = acc_rs[vv];
    }

    // C write (layout: col=lane&15, row=(lane>>4)*4+reg); nontemporal
    float* pbase = part + (size_t)kb * N_ROWS * D;
#pragma unroll
    for (int n = 0; n < 8; ++n) {
        int orow = i0 + wm * 16 + lq * 4;
        int ocol = wn * 128 + n * 16 + lr;
        float* op = pbase + (size_t)orow * D + ocol;
#pragma unroll
        for (int vv = 0; vv < 4; ++vv)
            __builtin_nontemporal_store(acc[n][vv], op + (size_t)vv * D);
    }
}

// K5: split-K reduce + epilogue (divide, elu, proj, logmap0, sigmoid, expmap0)
__global__ void k_final3(const float* __restrict__ part, const float* __restrict__ rspart,
                         float* __restrict__ out) {
    __shared__ float sb[4];
    int row = blockIdx.x, t = threadIdx.x;
    float raw = 0.f, rs = 0.f;
#pragma unroll
    for (int kbi = 0; kbi < NKB; ++kbi) {
        raw += part[((size_t)kbi * N_ROWS + row) * D + t];
        rs += rspart[(size_t)kbi * N_ROWS + row];
    }
    float hp = raw / rs;
    float ey = 0.f;
    if (t >= 1) ey = (hp > 0.f) ? hp : expm1f(hp);
    float ss = breduce_sum256(ey * ey, sb);
    float x0 = sqrtf(1.f + ss);
    float th = fmaxf(x0, 1.f + 1e-7f);
    float al = acoshf(th);
    float yn = fmaxf(sqrtf(ss), 1e-15f);
    float u = (t >= 1) ? (al * ey / yn) : 0.f;
    float s = 1.f / (1.f + expf(-u));
    float s2 = (t >= 1) ? s * s : 0.f;
    float ssn = breduce_sum256(s2, sb);
    float xn = fmaxf(sqrtf(ssn), 1e-15f);
    float sh = sinhf(xn);
    float yf = (t >= 1) ? (sh * s / xn) : 0.f;
    float sy = breduce_sum256(yf * yf, sb);
    float res = (t == 0) ? sqrtf(1.f + sy) : yf;
    out[(size_t)row * D + t] = res;
}

extern "C" void kernel_launch(void* const* d_in, const int* in_sizes, int n_in,
                              void* d_out, int out_size, void* d_ws, size_t ws_size,
                              hipStream_t stream) {
    const float* x    = (const float*)d_in[0];
    const int*   adj  = (const int*)d_in[1];
    const float* Wg   = (const float*)d_in[3];
    const float* Wa   = (const float*)d_in[4];
    const float* aatt = (const float*)d_in[5];
    float* out = (float*)d_out;

    char* wsb = (char*)d_ws;
    unsigned short* M2Thi  = (unsigned short*)(wsb);              // 128 KB
    unsigned short* M2Tlo  = (unsigned short*)(wsb + 0x0020000);  // 128 KB
    float*          v      = (float*)(wsb + 0x0040000);           // 1 KB
    unsigned short* wbf    = (unsigned short*)(wsb + 0x0048000);  // 16 KB
    unsigned short* Awhi   = (unsigned short*)(wsb + 0x0100000);  // 4 MB
    unsigned short* Awlo   = (unsigned short*)(wsb + 0x0500000);  // 4 MB
    unsigned short* GT     = (unsigned short*)(wsb + 0x0900000);  // 4 MB
    float*          rspart = (float*)(wsb + 0x0D00000);           // 128 KB
    float*          part   = (float*)(wsb + 0x1000000);           // 32 MB

    k_M2v<<<255, 256, 0, stream>>>(Wg, Wa, aatt, M2Thi, M2Tlo, v);
    k_logw<<<N_ROWS / 8, 256, 0, stream>>>(x, v, wbf, Awhi, Awlo);
    k_hGT<<<N_ROWS / 64, 512, 0, stream>>>(M2Thi, M2Tlo, Awhi, Awlo, GT);
    k_attadj<<<128 * NKB, 512, 0, stream>>>(adj, GT, wbf, part, rspart);
    k_final3<<<N_ROWS, 256, 0, stream>>>(part, rspart, out);
}